// Round 2
// baseline (1077.613 us; speedup 1.0000x reference)
//
#include <hip/hip_runtime.h>

// ---------------------------------------------------------------------------
// IDynamicDWConv pipeline, fp32 end-to-end.
//   x[2,64,256,256] -> avgpool4 -> 3x resblock(conv3x3 C64) @64x64
//   -> maxpool2 -> 3x resblock @32x32 -> conv1x1 64->576 = wt[2,576,32,32]
//   -> (bilinear x8 upsample fused into) dynamic depthwise 3x3 over x.
// R2: conv3x3/conv1x1 rewritten — weights staged in LDS (b128 broadcast
// reads, in-order lgkmcnt) instead of in-loop s_load (out-of-order SMEM
// forced lgkmcnt(0) full drains -> 6.6% VALUBusy). 4oc x 4px register tile.
// ---------------------------------------------------------------------------

__global__ __launch_bounds__(256) void avgpool4_k(const float* __restrict__ x,
                                                  float* __restrict__ y) {
    int idx = blockIdx.x * 256 + threadIdx.x;      // 2*64*64*64 = 524288
    int wo = idx & 63;
    int ho = (idx >> 6) & 63;
    int cz = idx >> 12;                            // n*64+c, 0..127
    const float* base = x + ((long)cz * 256 + ho * 4) * 256 + wo * 4;
    float s = 0.f;
#pragma unroll
    for (int r = 0; r < 4; ++r) {
        float4 v = *(const float4*)(base + r * 256);
        s += v.x + v.y + v.z + v.w;
    }
    y[idx] = s * 0.0625f;
}

__global__ __launch_bounds__(256) void maxpool2_k(const float* __restrict__ x,
                                                  float* __restrict__ y) {
    int idx = blockIdx.x * 256 + threadIdx.x;      // 2*64*32*32 = 131072
    int wo = idx & 31;
    int ho = (idx >> 5) & 31;
    int cz = idx >> 10;                            // n*64+c
    const float* base = x + ((long)cz * 64 + ho * 2) * 64 + wo * 2;
    float a = base[0], b = base[1], c = base[64], d = base[65];
    y[idx] = fmaxf(fmaxf(a, b), fmaxf(c, d));
}

// Direct 3x3 SAME conv, C_in=C_out=64.
// Block: 128 thr = 16x16 px tile x 8 oc. Thread: 4 oc x 4 px(w).
// Weights in LDS [ci][tap][8oc] -> float4 broadcast reads (wave-uniform addr).
// Input in LDS 16-ci chunks, 18x18 tile, row stride 19 (bank spread).
__global__ __launch_bounds__(128) void conv3x3_k(
    const float* __restrict__ in, const float* __restrict__ wgt,
    const float* __restrict__ bias, const float* __restrict__ res,
    float* __restrict__ out, int S, int lrelu) {
    __shared__ float s_w[64 * 72];                 // [ci][tap][8oc] 18432 B
    __shared__ float s_in[16 * 18 * 19];           // [ci][18r][19c]  21888 B
    const int tid = threadIdx.x;
    const int twx = tid & 3;                       // px quad along w
    const int ty  = (tid >> 2) & 15;               // output row
    const int ocg = tid >> 6;                      // oc quad (== wave id)
    const int tw = blockIdx.x * 16, th = blockIdx.y * 16;
    const int n = blockIdx.z >> 3;
    const int oc0 = (blockIdx.z & 7) * 8;
    const int px0 = twx * 4;

    // Stage all weights for this block's 8 oc: coalesced global read,
    // scattered (cheap, 36 instr) LDS write.
    for (int idx = tid; idx < 4608; idx += 128) {
        int k = idx / 576;                         // oc within group of 8
        int r = idx - k * 576;                     // ci*9 + tap
        int ci = r / 9;
        int tap = r - ci * 9;
        s_w[ci * 72 + tap * 8 + k] = wgt[(long)oc0 * 576 + idx];
    }

    float acc[4][4];
#pragma unroll
    for (int i = 0; i < 4; ++i)
#pragma unroll
        for (int j = 0; j < 4; ++j) acc[i][j] = 0.f;

    for (int chunk = 0; chunk < 64; chunk += 16) {
        __syncthreads();                           // covers s_w on iter 0
        for (int idx = tid; idx < 16 * 324; idx += 128) {
            int ci = idx / 324;
            int rem = idx - ci * 324;
            int r = rem / 18;
            int c = rem - r * 18;
            int gh = th + r - 1, gw = tw + c - 1;
            float v = 0.f;
            if ((unsigned)gh < (unsigned)S && (unsigned)gw < (unsigned)S)
                v = in[((long)(n * 64 + chunk + ci) * S + gh) * S + gw];
            s_in[ci * 342 + r * 19 + c] = v;
        }
        __syncthreads();
#pragma unroll 2
        for (int ci = 0; ci < 16; ++ci) {
            const float* sp = &s_in[ci * 342 + ty * 19 + px0];
            float xr[3][6];
#pragma unroll
            for (int r = 0; r < 3; ++r)
#pragma unroll
                for (int j = 0; j < 6; ++j)
                    xr[r][j] = sp[r * 19 + j];
            const float* wp = &s_w[(chunk + ci) * 72 + ocg * 4];
#pragma unroll
            for (int dh = 0; dh < 3; ++dh)
#pragma unroll
                for (int dw = 0; dw < 3; ++dw) {
                    float4 wv = *(const float4*)&wp[(dh * 3 + dw) * 8];
#pragma unroll
                    for (int p = 0; p < 4; ++p) {
                        float xv = xr[dh][p + dw];
                        acc[0][p] += xv * wv.x;
                        acc[1][p] += xv * wv.y;
                        acc[2][p] += xv * wv.z;
                        acc[3][p] += xv * wv.w;
                    }
                }
        }
    }

    const int h = th + ty;
#pragma unroll
    for (int k = 0; k < 4; ++k) {
        int oc = oc0 + ocg * 4 + k;
        float b = bias[oc];
        float4 v;
        v.x = acc[k][0] + b; v.y = acc[k][1] + b;
        v.z = acc[k][2] + b; v.w = acc[k][3] + b;
        if (lrelu) {
            v.x = v.x > 0.f ? v.x : 0.1f * v.x;
            v.y = v.y > 0.f ? v.y : 0.1f * v.y;
            v.z = v.z > 0.f ? v.z : 0.1f * v.z;
            v.w = v.w > 0.f ? v.w : 0.1f * v.w;
        }
        long off = ((long)(n * 64 + oc) * S + h) * S + tw + px0;
        if (res) {
            float4 r = *(const float4*)&res[off];
            v.x += r.x; v.y += r.y; v.z += r.z; v.w += r.w;
        }
        *(float4*)&out[off] = v;
    }
}

// 1x1 conv 64 -> 576 at 32x32. Block: 256 px, 8 oc. Weights in LDS.
__global__ __launch_bounds__(256) void conv1x1_k(
    const float* __restrict__ in, const float* __restrict__ w,
    const float* __restrict__ b, float* __restrict__ out) {
    __shared__ float s_in[32 * 256];               // 32 KB
    __shared__ float s_w[64 * 8];                  // [ci][8oc] 2 KB
    const int tid = threadIdx.x;
    const int p0 = blockIdx.x * 256;               // 4 tiles of 1024 px
    const int cog = blockIdx.y;                    // 72 groups of 8
    const int n = blockIdx.z;

    for (int idx = tid; idx < 512; idx += 256) {   // coalesced: w[cog*8 .. +8][64]
        int j = idx >> 6;
        int ci = idx & 63;
        s_w[ci * 8 + j] = w[(long)cog * 512 + idx];
    }

    float acc[8];
#pragma unroll
    for (int i = 0; i < 8; ++i) acc[i] = b[cog * 8 + i];

    for (int chunk = 0; chunk < 64; chunk += 32) {
        __syncthreads();                           // covers s_w on iter 0
#pragma unroll
        for (int i = 0; i < 32; ++i)
            s_in[i * 256 + tid] = in[(long)(n * 64 + chunk + i) * 1024 + p0 + tid];
        __syncthreads();
#pragma unroll 4
        for (int ci = 0; ci < 32; ++ci) {
            float v = s_in[ci * 256 + tid];
            float4 w0 = *(const float4*)&s_w[(chunk + ci) * 8];
            float4 w1 = *(const float4*)&s_w[(chunk + ci) * 8 + 4];
            acc[0] += v * w0.x; acc[1] += v * w0.y;
            acc[2] += v * w0.z; acc[3] += v * w0.w;
            acc[4] += v * w1.x; acc[5] += v * w1.y;
            acc[6] += v * w1.z; acc[7] += v * w1.w;
        }
    }
#pragma unroll
    for (int oc = 0; oc < 8; ++oc)
        out[(long)(n * 576 + cog * 8 + oc) * 1024 + p0 + tid] = acc[oc];
}

// Fused bilinear x8 upsample (half-pixel, edge clamp) + dynamic depthwise 3x3
// with replicate padding on x. One thread per output pixel.
__global__ __launch_bounds__(256) void dynconv_k(
    const float* __restrict__ x, const float* __restrict__ wt,
    float* __restrict__ out) {
    const int w = threadIdx.x;                     // 0..255
    const int h = blockIdx.x;                      // 0..255
    const int cz = blockIdx.y;                     // n*64+c, 0..127

    float src_h = h * 0.125f - 0.4375f;
    int h0 = (int)floorf(src_h);
    float fh = src_h - (float)h0;
    int h0c = min(max(h0, 0), 31), h1c = min(max(h0 + 1, 0), 31);
    float src_w = w * 0.125f - 0.4375f;
    int w0 = (int)floorf(src_w);
    float fw = src_w - (float)w0;
    int w0c = min(max(w0, 0), 31), w1c = min(max(w0 + 1, 0), 31);

    // wt channel base: n*576 + c*9 == (n*64+c)*9
    const float* wtb = wt + (long)cz * 9 * 1024;
    const float* xb = x + (long)cz * 65536;
    float acc = 0.f;
#pragma unroll
    for (int tap = 0; tap < 9; ++tap) {
        const float* p = wtb + tap * 1024;
        float w00 = p[h0c * 32 + w0c], w01 = p[h0c * 32 + w1c];
        float w10 = p[h1c * 32 + w0c], w11 = p[h1c * 32 + w1c];
        float top = w00 + fw * (w01 - w00);
        float bot = w10 + fw * (w11 - w10);
        float wv = top + fh * (bot - top);
        int dh = tap / 3, dw = tap - dh * 3;
        int hh = min(max(h + dh - 1, 0), 255);
        int ww = min(max(w + dw - 1, 0), 255);
        acc += xb[hh * 256 + ww] * wv;
    }
    out[(long)cz * 65536 + h * 256 + w] = acc;
}

extern "C" void kernel_launch(void* const* d_in, const int* in_sizes, int n_in,
                              void* d_out, int out_size, void* d_ws, size_t ws_size,
                              hipStream_t stream) {
    const float* x    = (const float*)d_in[0];
    const float* b1w1 = (const float*)d_in[1];
    const float* b1b1 = (const float*)d_in[2];
    const float* b1w2 = (const float*)d_in[3];
    const float* b1b2 = (const float*)d_in[4];
    const float* b2w1 = (const float*)d_in[5];
    const float* b2b1 = (const float*)d_in[6];
    const float* b2w2 = (const float*)d_in[7];
    const float* b2b2 = (const float*)d_in[8];
    const float* tokw = (const float*)d_in[9];
    const float* tokb = (const float*)d_in[10];
    float* out = (float*)d_out;
    float* ws = (float*)d_ws;

    // Stage 1 buffers: [2,64,64,64] = 524288 floats each.
    float* A = ws;
    float* B = ws + 524288;
    float* T = ws + 1048576;
    // Stage 2 buffers overlay A (dead after maxpool reads B):
    float* P = ws;                  // [2,64,32,32] = 131072
    float* Q = ws + 131072;
    float* U = ws + 262144;
    float* WT = ws + 393216;        // [2,576,32,32] = 1179648 floats

    const int WSZ = 64 * 64 * 9;    // per-resblock weight stride

    avgpool4_k<<<2048, 256, 0, stream>>>(x, A);

    dim3 g64(4, 4, 16);
    conv3x3_k<<<g64, 128, 0, stream>>>(A, b1w1 + 0 * WSZ, b1b1 + 0,   nullptr, T, 64, 1);
    conv3x3_k<<<g64, 128, 0, stream>>>(T, b1w2 + 0 * WSZ, b1b2 + 0,   A,       B, 64, 0);
    conv3x3_k<<<g64, 128, 0, stream>>>(B, b1w1 + 1 * WSZ, b1b1 + 64,  nullptr, T, 64, 1);
    conv3x3_k<<<g64, 128, 0, stream>>>(T, b1w2 + 1 * WSZ, b1b2 + 64,  B,       A, 64, 0);
    conv3x3_k<<<g64, 128, 0, stream>>>(A, b1w1 + 2 * WSZ, b1b1 + 128, nullptr, T, 64, 1);
    conv3x3_k<<<g64, 128, 0, stream>>>(T, b1w2 + 2 * WSZ, b1b2 + 128, A,       B, 64, 0);

    maxpool2_k<<<512, 256, 0, stream>>>(B, P);

    dim3 g32(2, 2, 16);
    conv3x3_k<<<g32, 128, 0, stream>>>(P, b2w1 + 0 * WSZ, b2b1 + 0,   nullptr, U, 32, 1);
    conv3x3_k<<<g32, 128, 0, stream>>>(U, b2w2 + 0 * WSZ, b2b2 + 0,   P,       Q, 32, 0);
    conv3x3_k<<<g32, 128, 0, stream>>>(Q, b2w1 + 1 * WSZ, b2b1 + 64,  nullptr, U, 32, 1);
    conv3x3_k<<<g32, 128, 0, stream>>>(U, b2w2 + 1 * WSZ, b2b2 + 64,  Q,       P, 32, 0);
    conv3x3_k<<<g32, 128, 0, stream>>>(P, b2w1 + 2 * WSZ, b2b1 + 128, nullptr, U, 32, 1);
    conv3x3_k<<<g32, 128, 0, stream>>>(U, b2w2 + 2 * WSZ, b2b2 + 128, P,       Q, 32, 0);

    conv1x1_k<<<dim3(4, 72, 2), 256, 0, stream>>>(Q, tokw, tokb, WT);

    dynconv_k<<<dim3(256, 128), 256, 0, stream>>>(x, WT, out);
}

// Round 3
// 727.087 us; speedup vs baseline: 1.4821x; 1.4821x over previous
//
#include <hip/hip_runtime.h>

// ---------------------------------------------------------------------------
// IDynamicDWConv pipeline, fp32 end-to-end.
// R3: conv3x3 re-tiled for OCCUPANCY. R2 failed because grid=256 blocks of
// 128 thr = 0.5 waves/SIMD (latency fully exposed, VALUBusy 11%). Now:
// thread = 1px x 4oc (4 acc), block = 256 thr = 16x16 px x 4 oc,
// grid(S=64) = 512 blocks -> 2 blocks/CU, 8 waves/CU. Weights stay in LDS
// ([ci][tap][4oc] -> wave-uniform float4 broadcast reads).
// ---------------------------------------------------------------------------

__global__ __launch_bounds__(256) void avgpool4_k(const float* __restrict__ x,
                                                  float* __restrict__ y) {
    int idx = blockIdx.x * 256 + threadIdx.x;      // 2*64*64*64 = 524288
    int wo = idx & 63;
    int ho = (idx >> 6) & 63;
    int cz = idx >> 12;                            // n*64+c, 0..127
    const float* base = x + ((long)cz * 256 + ho * 4) * 256 + wo * 4;
    float s = 0.f;
#pragma unroll
    for (int r = 0; r < 4; ++r) {
        float4 v = *(const float4*)(base + r * 256);
        s += v.x + v.y + v.z + v.w;
    }
    y[idx] = s * 0.0625f;
}

__global__ __launch_bounds__(256) void maxpool2_k(const float* __restrict__ x,
                                                  float* __restrict__ y) {
    int idx = blockIdx.x * 256 + threadIdx.x;      // 2*64*32*32 = 131072
    int wo = idx & 31;
    int ho = (idx >> 5) & 31;
    int cz = idx >> 10;                            // n*64+c
    const float* base = x + ((long)cz * 64 + ho * 2) * 64 + wo * 2;
    float a = base[0], b = base[1], c = base[64], d = base[65];
    y[idx] = fmaxf(fmaxf(a, b), fmaxf(c, d));
}

// Direct 3x3 SAME conv, C_in=C_out=64.
// Block: 256 thr = 16x16 px tile x 4 oc; thread: 1 px x 4 oc (4 acc).
// s_w [ci][tap][4oc] -> float4 wave-uniform broadcast reads.
// s_in 16-ci chunks, 18x18 tile, row stride 19.
__global__ __launch_bounds__(256, 2) void conv3x3_k(
    const float* __restrict__ in, const float* __restrict__ wgt,
    const float* __restrict__ bias, const float* __restrict__ res,
    float* __restrict__ out, int S, int lrelu) {
    __shared__ __align__(16) float s_w[64 * 36];   // [ci][tap][4oc] 9216 B
    __shared__ float s_in[16 * 342];               // [ci][18r][19c] 21888 B
    const int tid = threadIdx.x;
    const int tx = tid & 15;                       // output col within tile
    const int ty = tid >> 4;                       // output row within tile
    const int tw = blockIdx.x * 16, th = blockIdx.y * 16;
    const int n = blockIdx.z >> 4;
    const int oc0 = (blockIdx.z & 15) * 4;

    // Stage this block's 4 oc of weights: [k][ci][tap] -> [ci][tap][k]
    for (int idx = tid; idx < 2304; idx += 256) {
        int k = idx / 576;                         // oc within group of 4
        int r = idx - k * 576;                     // ci*9 + tap
        int ci = r / 9;
        int tap = r - ci * 9;
        s_w[ci * 36 + tap * 4 + k] = wgt[(long)oc0 * 576 + idx];
    }

    float acc[4] = {0.f, 0.f, 0.f, 0.f};

    for (int chunk = 0; chunk < 64; chunk += 16) {
        __syncthreads();                           // covers s_w on iter 0
        for (int idx = tid; idx < 16 * 324; idx += 256) {
            int ci = idx / 324;
            int rem = idx - ci * 324;
            int r = rem / 18;
            int c = rem - r * 18;
            int gh = th + r - 1, gw = tw + c - 1;
            float v = 0.f;
            if ((unsigned)gh < (unsigned)S && (unsigned)gw < (unsigned)S)
                v = in[((long)(n * 64 + chunk + ci) * S + gh) * S + gw];
            s_in[ci * 342 + r * 19 + c] = v;
        }
        __syncthreads();
#pragma unroll 2
        for (int ci = 0; ci < 16; ++ci) {
            const float* sp = &s_in[ci * 342 + ty * 19 + tx];
            float xw[9];
#pragma unroll
            for (int r = 0; r < 3; ++r)
#pragma unroll
                for (int c = 0; c < 3; ++c)
                    xw[r * 3 + c] = sp[r * 19 + c];
            const float* wp = &s_w[(chunk + ci) * 36];
#pragma unroll
            for (int t = 0; t < 9; ++t) {
                float4 wv = *(const float4*)&wp[t * 4];
                float xv = xw[t];
                acc[0] += xv * wv.x;
                acc[1] += xv * wv.y;
                acc[2] += xv * wv.z;
                acc[3] += xv * wv.w;
            }
        }
    }

    const int h = th + ty, w = tw + tx;
#pragma unroll
    for (int k = 0; k < 4; ++k) {
        int oc = oc0 + k;
        float v = acc[k] + bias[oc];
        if (lrelu) v = v > 0.f ? v : 0.1f * v;
        long off = ((long)(n * 64 + oc) * S + h) * S + w;
        if (res) v += res[off];
        out[off] = v;
    }
}

// 1x1 conv 64 -> 576 at 32x32. Block: 256 px, 8 oc. Weights in LDS.
__global__ __launch_bounds__(256) void conv1x1_k(
    const float* __restrict__ in, const float* __restrict__ w,
    const float* __restrict__ b, float* __restrict__ out) {
    __shared__ float s_in[32 * 256];               // 32 KB
    __shared__ __align__(16) float s_w[64 * 8];    // [ci][8oc] 2 KB
    const int tid = threadIdx.x;
    const int p0 = blockIdx.x * 256;               // 4 tiles of 1024 px
    const int cog = blockIdx.y;                    // 72 groups of 8
    const int n = blockIdx.z;

    for (int idx = tid; idx < 512; idx += 256) {   // coalesced: w[cog*8 .. +8][64]
        int j = idx >> 6;
        int ci = idx & 63;
        s_w[ci * 8 + j] = w[(long)cog * 512 + idx];
    }

    float acc[8];
#pragma unroll
    for (int i = 0; i < 8; ++i) acc[i] = b[cog * 8 + i];

    for (int chunk = 0; chunk < 64; chunk += 32) {
        __syncthreads();                           // covers s_w on iter 0
#pragma unroll
        for (int i = 0; i < 32; ++i)
            s_in[i * 256 + tid] = in[(long)(n * 64 + chunk + i) * 1024 + p0 + tid];
        __syncthreads();
#pragma unroll 4
        for (int ci = 0; ci < 32; ++ci) {
            float v = s_in[ci * 256 + tid];
            float4 w0 = *(const float4*)&s_w[(chunk + ci) * 8];
            float4 w1 = *(const float4*)&s_w[(chunk + ci) * 8 + 4];
            acc[0] += v * w0.x; acc[1] += v * w0.y;
            acc[2] += v * w0.z; acc[3] += v * w0.w;
            acc[4] += v * w1.x; acc[5] += v * w1.y;
            acc[6] += v * w1.z; acc[7] += v * w1.w;
        }
    }
#pragma unroll
    for (int oc = 0; oc < 8; ++oc)
        out[(long)(n * 576 + cog * 8 + oc) * 1024 + p0 + tid] = acc[oc];
}

// Fused bilinear x8 upsample (half-pixel, edge clamp) + dynamic depthwise 3x3
// with replicate padding on x. One thread per output pixel.
__global__ __launch_bounds__(256) void dynconv_k(
    const float* __restrict__ x, const float* __restrict__ wt,
    float* __restrict__ out) {
    const int w = threadIdx.x;                     // 0..255
    const int h = blockIdx.x;                      // 0..255
    const int cz = blockIdx.y;                     // n*64+c, 0..127

    float src_h = h * 0.125f - 0.4375f;
    int h0 = (int)floorf(src_h);
    float fh = src_h - (float)h0;
    int h0c = min(max(h0, 0), 31), h1c = min(max(h0 + 1, 0), 31);
    float src_w = w * 0.125f - 0.4375f;
    int w0 = (int)floorf(src_w);
    float fw = src_w - (float)w0;
    int w0c = min(max(w0, 0), 31), w1c = min(max(w0 + 1, 0), 31);

    // wt channel base: n*576 + c*9 == (n*64+c)*9
    const float* wtb = wt + (long)cz * 9 * 1024;
    const float* xb = x + (long)cz * 65536;
    float acc = 0.f;
#pragma unroll
    for (int tap = 0; tap < 9; ++tap) {
        const float* p = wtb + tap * 1024;
        float w00 = p[h0c * 32 + w0c], w01 = p[h0c * 32 + w1c];
        float w10 = p[h1c * 32 + w0c], w11 = p[h1c * 32 + w1c];
        float top = w00 + fw * (w01 - w00);
        float bot = w10 + fw * (w11 - w10);
        float wv = top + fh * (bot - top);
        int dh = tap / 3, dw = tap - dh * 3;
        int hh = min(max(h + dh - 1, 0), 255);
        int ww = min(max(w + dw - 1, 0), 255);
        acc += xb[hh * 256 + ww] * wv;
    }
    out[(long)cz * 65536 + h * 256 + w] = acc;
}

extern "C" void kernel_launch(void* const* d_in, const int* in_sizes, int n_in,
                              void* d_out, int out_size, void* d_ws, size_t ws_size,
                              hipStream_t stream) {
    const float* x    = (const float*)d_in[0];
    const float* b1w1 = (const float*)d_in[1];
    const float* b1b1 = (const float*)d_in[2];
    const float* b1w2 = (const float*)d_in[3];
    const float* b1b2 = (const float*)d_in[4];
    const float* b2w1 = (const float*)d_in[5];
    const float* b2b1 = (const float*)d_in[6];
    const float* b2w2 = (const float*)d_in[7];
    const float* b2b2 = (const float*)d_in[8];
    const float* tokw = (const float*)d_in[9];
    const float* tokb = (const float*)d_in[10];
    float* out = (float*)d_out;
    float* ws = (float*)d_ws;

    // Stage 1 buffers: [2,64,64,64] = 524288 floats each.
    float* A = ws;
    float* B = ws + 524288;
    float* T = ws + 1048576;
    // Stage 2 buffers overlay A (dead after maxpool reads B):
    float* P = ws;                  // [2,64,32,32] = 131072
    float* Q = ws + 131072;
    float* U = ws + 262144;
    float* WT = ws + 393216;        // [2,576,32,32] = 1179648 floats

    const int WSZ = 64 * 64 * 9;    // per-resblock weight stride

    avgpool4_k<<<2048, 256, 0, stream>>>(x, A);

    dim3 g64(4, 4, 32);
    conv3x3_k<<<g64, 256, 0, stream>>>(A, b1w1 + 0 * WSZ, b1b1 + 0,   nullptr, T, 64, 1);
    conv3x3_k<<<g64, 256, 0, stream>>>(T, b1w2 + 0 * WSZ, b1b2 + 0,   A,       B, 64, 0);
    conv3x3_k<<<g64, 256, 0, stream>>>(B, b1w1 + 1 * WSZ, b1b1 + 64,  nullptr, T, 64, 1);
    conv3x3_k<<<g64, 256, 0, stream>>>(T, b1w2 + 1 * WSZ, b1b2 + 64,  B,       A, 64, 0);
    conv3x3_k<<<g64, 256, 0, stream>>>(A, b1w1 + 2 * WSZ, b1b1 + 128, nullptr, T, 64, 1);
    conv3x3_k<<<g64, 256, 0, stream>>>(T, b1w2 + 2 * WSZ, b1b2 + 128, A,       B, 64, 0);

    maxpool2_k<<<512, 256, 0, stream>>>(B, P);

    dim3 g32(2, 2, 32);
    conv3x3_k<<<g32, 256, 0, stream>>>(P, b2w1 + 0 * WSZ, b2b1 + 0,   nullptr, U, 32, 1);
    conv3x3_k<<<g32, 256, 0, stream>>>(U, b2w2 + 0 * WSZ, b2b2 + 0,   P,       Q, 32, 0);
    conv3x3_k<<<g32, 256, 0, stream>>>(Q, b2w1 + 1 * WSZ, b2b1 + 64,  nullptr, U, 32, 1);
    conv3x3_k<<<g32, 256, 0, stream>>>(U, b2w2 + 1 * WSZ, b2b2 + 64,  Q,       P, 32, 0);
    conv3x3_k<<<g32, 256, 0, stream>>>(P, b2w1 + 2 * WSZ, b2b1 + 128, nullptr, U, 32, 1);
    conv3x3_k<<<g32, 256, 0, stream>>>(U, b2w2 + 2 * WSZ, b2b2 + 128, P,       Q, 32, 0);

    conv1x1_k<<<dim3(4, 72, 2), 256, 0, stream>>>(Q, tokw, tokb, WT);

    dynconv_k<<<dim3(256, 128), 256, 0, stream>>>(x, WT, out);
}

// Round 4
// 430.574 us; speedup vs baseline: 2.5027x; 1.6886x over previous
//
#include <hip/hip_runtime.h>

// ---------------------------------------------------------------------------
// IDynamicDWConv pipeline, fp32 end-to-end.
// R4: conv3x3 staging software-pipelined. R3 was latency-bound: per chunk,
// ~20 global loads/thread had to drain before the barrier, 4x per block,
// nothing overlapping (VALUBusy 33%, HBM 1.8%). Now: per-thread offsets +
// validity precomputed once; chunk k+1's loads issue right after the barrier
// and complete during chunk k's compute (vmcnt wait lands at next LDS write).
// Also: S templated (const addr math), OCB=2 for S=32 (grid 128->256 blocks).
// ---------------------------------------------------------------------------

__global__ __launch_bounds__(256) void avgpool4_k(const float* __restrict__ x,
                                                  float* __restrict__ y) {
    int idx = blockIdx.x * 256 + threadIdx.x;      // 2*64*64*64 = 524288
    int wo = idx & 63;
    int ho = (idx >> 6) & 63;
    int cz = idx >> 12;                            // n*64+c, 0..127
    const float* base = x + ((long)cz * 256 + ho * 4) * 256 + wo * 4;
    float s = 0.f;
#pragma unroll
    for (int r = 0; r < 4; ++r) {
        float4 v = *(const float4*)(base + r * 256);
        s += v.x + v.y + v.z + v.w;
    }
    y[idx] = s * 0.0625f;
}

__global__ __launch_bounds__(256) void maxpool2_k(const float* __restrict__ x,
                                                  float* __restrict__ y) {
    int idx = blockIdx.x * 256 + threadIdx.x;      // 2*64*32*32 = 131072
    int wo = idx & 31;
    int ho = (idx >> 5) & 31;
    int cz = idx >> 10;                            // n*64+c
    const float* base = x + ((long)cz * 64 + ho * 2) * 64 + wo * 2;
    float a = base[0], b = base[1], c = base[64], d = base[65];
    y[idx] = fmaxf(fmaxf(a, b), fmaxf(c, d));
}

// Direct 3x3 SAME conv, C_in=C_out=64, fp32.
// Block: 256 thr = 16x16 px tile x OCB oc; thread: 1 px x OCB acc.
// s_w [ci][tap][OCB] -> wave-uniform vector broadcast reads.
// s_in 16-ci chunks [ci][18r][19c]; staging reg-prefetched across chunks.
template <int S, int OCB>
__global__ __launch_bounds__(256) void conv3x3_t(
    const float* __restrict__ in, const float* __restrict__ wgt,
    const float* __restrict__ bias, const float* __restrict__ res,
    float* __restrict__ out, int lrelu) {
    __shared__ __align__(16) float s_w[64 * 9 * OCB];
    __shared__ float s_in[16 * 342];               // [ci][18r][19c]
    const int tid = threadIdx.x;
    const int tx = tid & 15;
    const int ty = tid >> 4;
    const int tw = blockIdx.x * 16, th = blockIdx.y * 16;
    const int n = blockIdx.z / (64 / OCB);
    const int oc0 = (blockIdx.z % (64 / OCB)) * OCB;

    // Stage this block's OCB oc of weights: [k][ci][tap] -> [ci][tap][k]
    for (int idx = tid; idx < OCB * 576; idx += 256) {
        int k = idx / 576;
        int r = idx - k * 576;
        int ci = r / 9;
        int tap = r - ci * 9;
        s_w[(ci * 9 + tap) * OCB + k] = wgt[(long)oc0 * 576 + idx];
    }

    // Precompute staging offsets once. 16 ci x 324 px = 5184 elems / 256 thr.
    constexpr int NLD = 21;                        // ceil(5184/256)
    int g_off[NLD];                                // clamped global offset
    int l_off[NLD];                                // LDS offset
    unsigned vmask = 0;                            // in-bounds bit per slot
#pragma unroll
    for (int j = 0; j < NLD; ++j) {
        int idx = tid + j * 256;
        int t = idx < 5184 ? idx : 5183;
        int ci = t / 324;
        int rem = t - ci * 324;
        int r = rem / 18;
        int c = rem - r * 18;
        int gh = th + r - 1, gw = tw + c - 1;
        if (idx < 5184 && (unsigned)gh < (unsigned)S && (unsigned)gw < (unsigned)S)
            vmask |= (1u << j);
        int ghc = gh < 0 ? 0 : (gh > S - 1 ? S - 1 : gh);
        int gwc = gw < 0 ? 0 : (gw > S - 1 ? S - 1 : gw);
        g_off[j] = ci * S * S + ghc * S + gwc;
        l_off[j] = ci * 342 + r * 19 + c;
    }

    const float* inb = in + (long)n * 64 * S * S;
    float pf[NLD];
#pragma unroll
    for (int j = 0; j < NLD; ++j) pf[j] = inb[g_off[j]];   // prefetch chunk 0

    float acc[OCB];
#pragma unroll
    for (int k = 0; k < OCB; ++k) acc[k] = 0.f;

    for (int chunk = 0; chunk < 64; chunk += 16) {
        __syncthreads();                           // LDS consumers done
#pragma unroll
        for (int j = 0; j < NLD; ++j) {
            float v = ((vmask >> j) & 1u) ? pf[j] : 0.f;
            if (j < 20 || tid < 64) s_in[l_off[j]] = v;
        }
        __syncthreads();                           // LDS ready
        if (chunk + 16 < 64) {                     // prefetch next chunk:
            const float* nb = inb + (chunk + 16) * S * S;
#pragma unroll
            for (int j = 0; j < NLD; ++j) pf[j] = nb[g_off[j]];
        }
#pragma unroll 4
        for (int ci = 0; ci < 16; ++ci) {
            const float* sp = &s_in[ci * 342 + ty * 19 + tx];
            float xw[9];
#pragma unroll
            for (int r = 0; r < 3; ++r)
#pragma unroll
                for (int c = 0; c < 3; ++c)
                    xw[r * 3 + c] = sp[r * 19 + c];
            const float* wp = &s_w[(chunk + ci) * 9 * OCB];
#pragma unroll
            for (int t = 0; t < 9; ++t) {
                float xv = xw[t];
                if constexpr (OCB == 4) {
                    float4 wv = *(const float4*)&wp[t * 4];
                    acc[0] += xv * wv.x;
                    acc[1] += xv * wv.y;
                    acc[2] += xv * wv.z;
                    acc[3] += xv * wv.w;
                } else {
                    float2 wv = *(const float2*)&wp[t * 2];
                    acc[0] += xv * wv.x;
                    acc[1] += xv * wv.y;
                }
            }
        }
    }

    const int h = th + ty, w = tw + tx;
#pragma unroll
    for (int k = 0; k < OCB; ++k) {
        int oc = oc0 + k;
        float v = acc[k] + bias[oc];
        if (lrelu) v = v > 0.f ? v : 0.1f * v;
        long off = ((long)(n * 64 + oc) * S + h) * S + w;
        if (res) v += res[off];
        out[off] = v;
    }
}

// 1x1 conv 64 -> 576 at 32x32. Block: 256 px, 8 oc. Weights in LDS.
__global__ __launch_bounds__(256) void conv1x1_k(
    const float* __restrict__ in, const float* __restrict__ w,
    const float* __restrict__ b, float* __restrict__ out) {
    __shared__ float s_in[32 * 256];               // 32 KB
    __shared__ __align__(16) float s_w[64 * 8];    // [ci][8oc] 2 KB
    const int tid = threadIdx.x;
    const int p0 = blockIdx.x * 256;               // 4 tiles of 1024 px
    const int cog = blockIdx.y;                    // 72 groups of 8
    const int n = blockIdx.z;

    for (int idx = tid; idx < 512; idx += 256) {   // coalesced: w[cog*8 .. +8][64]
        int j = idx >> 6;
        int ci = idx & 63;
        s_w[ci * 8 + j] = w[(long)cog * 512 + idx];
    }

    float acc[8];
#pragma unroll
    for (int i = 0; i < 8; ++i) acc[i] = b[cog * 8 + i];

    // prefetch chunk 0 into regs, pipeline across the 2 chunks
    float pf[32];
#pragma unroll
    for (int i = 0; i < 32; ++i)
        pf[i] = in[(long)(n * 64 + i) * 1024 + p0 + tid];

    for (int chunk = 0; chunk < 64; chunk += 32) {
        __syncthreads();
#pragma unroll
        for (int i = 0; i < 32; ++i) s_in[i * 256 + tid] = pf[i];
        __syncthreads();
        if (chunk + 32 < 64) {
#pragma unroll
            for (int i = 0; i < 32; ++i)
                pf[i] = in[(long)(n * 64 + chunk + 32 + i) * 1024 + p0 + tid];
        }
#pragma unroll 4
        for (int ci = 0; ci < 32; ++ci) {
            float v = s_in[ci * 256 + tid];
            float4 w0 = *(const float4*)&s_w[(chunk + ci) * 8];
            float4 w1 = *(const float4*)&s_w[(chunk + ci) * 8 + 4];
            acc[0] += v * w0.x; acc[1] += v * w0.y;
            acc[2] += v * w0.z; acc[3] += v * w0.w;
            acc[4] += v * w1.x; acc[5] += v * w1.y;
            acc[6] += v * w1.z; acc[7] += v * w1.w;
        }
    }
#pragma unroll
    for (int oc = 0; oc < 8; ++oc)
        out[(long)(n * 576 + cog * 8 + oc) * 1024 + p0 + tid] = acc[oc];
}

// Fused bilinear x8 upsample (half-pixel, edge clamp) + dynamic depthwise 3x3
// with replicate padding on x. One thread per output pixel.
__global__ __launch_bounds__(256) void dynconv_k(
    const float* __restrict__ x, const float* __restrict__ wt,
    float* __restrict__ out) {
    const int w = threadIdx.x;                     // 0..255
    const int h = blockIdx.x;                      // 0..255
    const int cz = blockIdx.y;                     // n*64+c, 0..127

    float src_h = h * 0.125f - 0.4375f;
    int h0 = (int)floorf(src_h);
    float fh = src_h - (float)h0;
    int h0c = min(max(h0, 0), 31), h1c = min(max(h0 + 1, 0), 31);
    float src_w = w * 0.125f - 0.4375f;
    int w0 = (int)floorf(src_w);
    float fw = src_w - (float)w0;
    int w0c = min(max(w0, 0), 31), w1c = min(max(w0 + 1, 0), 31);

    // wt channel base: n*576 + c*9 == (n*64+c)*9
    const float* wtb = wt + (long)cz * 9 * 1024;
    const float* xb = x + (long)cz * 65536;
    float acc = 0.f;
#pragma unroll
    for (int tap = 0; tap < 9; ++tap) {
        const float* p = wtb + tap * 1024;
        float w00 = p[h0c * 32 + w0c], w01 = p[h0c * 32 + w1c];
        float w10 = p[h1c * 32 + w0c], w11 = p[h1c * 32 + w1c];
        float top = w00 + fw * (w01 - w00);
        float bot = w10 + fw * (w11 - w10);
        float wv = top + fh * (bot - top);
        int dh = tap / 3, dw = tap - dh * 3;
        int hh = min(max(h + dh - 1, 0), 255);
        int ww = min(max(w + dw - 1, 0), 255);
        acc += xb[hh * 256 + ww] * wv;
    }
    out[(long)cz * 65536 + h * 256 + w] = acc;
}

extern "C" void kernel_launch(void* const* d_in, const int* in_sizes, int n_in,
                              void* d_out, int out_size, void* d_ws, size_t ws_size,
                              hipStream_t stream) {
    const float* x    = (const float*)d_in[0];
    const float* b1w1 = (const float*)d_in[1];
    const float* b1b1 = (const float*)d_in[2];
    const float* b1w2 = (const float*)d_in[3];
    const float* b1b2 = (const float*)d_in[4];
    const float* b2w1 = (const float*)d_in[5];
    const float* b2b1 = (const float*)d_in[6];
    const float* b2w2 = (const float*)d_in[7];
    const float* b2b2 = (const float*)d_in[8];
    const float* tokw = (const float*)d_in[9];
    const float* tokb = (const float*)d_in[10];
    float* out = (float*)d_out;
    float* ws = (float*)d_ws;

    // Stage 1 buffers: [2,64,64,64] = 524288 floats each.
    float* A = ws;
    float* B = ws + 524288;
    float* T = ws + 1048576;
    // Stage 2 buffers overlay A (dead after maxpool reads B):
    float* P = ws;                  // [2,64,32,32] = 131072
    float* Q = ws + 131072;
    float* U = ws + 262144;
    float* WT = ws + 393216;        // [2,576,32,32] = 1179648 floats

    const int WSZ = 64 * 64 * 9;    // per-resblock weight stride

    avgpool4_k<<<2048, 256, 0, stream>>>(x, A);

    dim3 g64(4, 4, 32);             // z = n*16 + ocg (OCB=4)
    conv3x3_t<64, 4><<<g64, 256, 0, stream>>>(A, b1w1 + 0 * WSZ, b1b1 + 0,   nullptr, T, 1);
    conv3x3_t<64, 4><<<g64, 256, 0, stream>>>(T, b1w2 + 0 * WSZ, b1b2 + 0,   A,       B, 0);
    conv3x3_t<64, 4><<<g64, 256, 0, stream>>>(B, b1w1 + 1 * WSZ, b1b1 + 64,  nullptr, T, 1);
    conv3x3_t<64, 4><<<g64, 256, 0, stream>>>(T, b1w2 + 1 * WSZ, b1b2 + 64,  B,       A, 0);
    conv3x3_t<64, 4><<<g64, 256, 0, stream>>>(A, b1w1 + 2 * WSZ, b1b1 + 128, nullptr, T, 1);
    conv3x3_t<64, 4><<<g64, 256, 0, stream>>>(T, b1w2 + 2 * WSZ, b1b2 + 128, A,       B, 0);

    maxpool2_k<<<512, 256, 0, stream>>>(B, P);

    dim3 g32(2, 2, 64);             // z = n*32 + ocg (OCB=2)
    conv3x3_t<32, 2><<<g32, 256, 0, stream>>>(P, b2w1 + 0 * WSZ, b2b1 + 0,   nullptr, U, 1);
    conv3x3_t<32, 2><<<g32, 256, 0, stream>>>(U, b2w2 + 0 * WSZ, b2b2 + 0,   P,       Q, 0);
    conv3x3_t<32, 2><<<g32, 256, 0, stream>>>(Q, b2w1 + 1 * WSZ, b2b1 + 64,  nullptr, U, 1);
    conv3x3_t<32, 2><<<g32, 256, 0, stream>>>(U, b2w2 + 1 * WSZ, b2b2 + 64,  Q,       P, 0);
    conv3x3_t<32, 2><<<g32, 256, 0, stream>>>(P, b2w1 + 2 * WSZ, b2b1 + 128, nullptr, U, 1);
    conv3x3_t<32, 2><<<g32, 256, 0, stream>>>(U, b2w2 + 2 * WSZ, b2b2 + 128, P,       Q, 0);

    conv1x1_k<<<dim3(4, 72, 2), 256, 0, stream>>>(Q, tokw, tokb, WT);

    dynconv_k<<<dim3(256, 128), 256, 0, stream>>>(x, WT, out);
}

// Round 5
// 411.079 us; speedup vs baseline: 2.6214x; 1.0474x over previous
//
#include <hip/hip_runtime.h>

// ---------------------------------------------------------------------------
// IDynamicDWConv pipeline, fp32 end-to-end.
// R5: dynconv rewritten. R4 counters: 52 us, FETCH 67 MB (~2x x over-fetch,
// halo rows re-fetched across XCDs), 36 scattered wt loads + ~80 VALU per
// single output. Now: thread = 4 w-px (float4 store), 8h x 128w tile per cz,
// x tile staged in LDS (5.3 KB incl. replicate halo). 4-aligned w-strip
// shares floor(src_w) -> 4 outputs share all 4 bilinear corners per tap;
// h-lerp first (shared fh), then 4 cheap w-lerps. Convs untouched (no
// counters for them this round).
// ---------------------------------------------------------------------------

__global__ __launch_bounds__(256) void avgpool4_k(const float* __restrict__ x,
                                                  float* __restrict__ y) {
    int idx = blockIdx.x * 256 + threadIdx.x;      // 2*64*64*64 = 524288
    int wo = idx & 63;
    int ho = (idx >> 6) & 63;
    int cz = idx >> 12;                            // n*64+c, 0..127
    const float* base = x + ((long)cz * 256 + ho * 4) * 256 + wo * 4;
    float s = 0.f;
#pragma unroll
    for (int r = 0; r < 4; ++r) {
        float4 v = *(const float4*)(base + r * 256);
        s += v.x + v.y + v.z + v.w;
    }
    y[idx] = s * 0.0625f;
}

__global__ __launch_bounds__(256) void maxpool2_k(const float* __restrict__ x,
                                                  float* __restrict__ y) {
    int idx = blockIdx.x * 256 + threadIdx.x;      // 2*64*32*32 = 131072
    int wo = idx & 31;
    int ho = (idx >> 5) & 31;
    int cz = idx >> 10;                            // n*64+c
    const float* base = x + ((long)cz * 64 + ho * 2) * 64 + wo * 2;
    float a = base[0], b = base[1], c = base[64], d = base[65];
    y[idx] = fmaxf(fmaxf(a, b), fmaxf(c, d));
}

// Direct 3x3 SAME conv, C_in=C_out=64, fp32.
// Block: 256 thr = 16x16 px tile x OCB oc; thread: 1 px x OCB acc.
// s_w [ci][tap][OCB] -> wave-uniform vector broadcast reads.
// s_in 16-ci chunks [ci][18r][19c]; staging reg-prefetched across chunks.
template <int S, int OCB>
__global__ __launch_bounds__(256) void conv3x3_t(
    const float* __restrict__ in, const float* __restrict__ wgt,
    const float* __restrict__ bias, const float* __restrict__ res,
    float* __restrict__ out, int lrelu) {
    __shared__ __align__(16) float s_w[64 * 9 * OCB];
    __shared__ float s_in[16 * 342];               // [ci][18r][19c]
    const int tid = threadIdx.x;
    const int tx = tid & 15;
    const int ty = tid >> 4;
    const int tw = blockIdx.x * 16, th = blockIdx.y * 16;
    const int n = blockIdx.z / (64 / OCB);
    const int oc0 = (blockIdx.z % (64 / OCB)) * OCB;

    // Stage this block's OCB oc of weights: [k][ci][tap] -> [ci][tap][k]
    for (int idx = tid; idx < OCB * 576; idx += 256) {
        int k = idx / 576;
        int r = idx - k * 576;
        int ci = r / 9;
        int tap = r - ci * 9;
        s_w[(ci * 9 + tap) * OCB + k] = wgt[(long)oc0 * 576 + idx];
    }

    // Precompute staging offsets once. 16 ci x 324 px = 5184 elems / 256 thr.
    constexpr int NLD = 21;                        // ceil(5184/256)
    int g_off[NLD];                                // clamped global offset
    int l_off[NLD];                                // LDS offset
    unsigned vmask = 0;                            // in-bounds bit per slot
#pragma unroll
    for (int j = 0; j < NLD; ++j) {
        int idx = tid + j * 256;
        int t = idx < 5184 ? idx : 5183;
        int ci = t / 324;
        int rem = t - ci * 324;
        int r = rem / 18;
        int c = rem - r * 18;
        int gh = th + r - 1, gw = tw + c - 1;
        if (idx < 5184 && (unsigned)gh < (unsigned)S && (unsigned)gw < (unsigned)S)
            vmask |= (1u << j);
        int ghc = gh < 0 ? 0 : (gh > S - 1 ? S - 1 : gh);
        int gwc = gw < 0 ? 0 : (gw > S - 1 ? S - 1 : gw);
        g_off[j] = ci * S * S + ghc * S + gwc;
        l_off[j] = ci * 342 + r * 19 + c;
    }

    const float* inb = in + (long)n * 64 * S * S;
    float pf[NLD];
#pragma unroll
    for (int j = 0; j < NLD; ++j) pf[j] = inb[g_off[j]];   // prefetch chunk 0

    float acc[OCB];
#pragma unroll
    for (int k = 0; k < OCB; ++k) acc[k] = 0.f;

    for (int chunk = 0; chunk < 64; chunk += 16) {
        __syncthreads();                           // LDS consumers done
#pragma unroll
        for (int j = 0; j < NLD; ++j) {
            float v = ((vmask >> j) & 1u) ? pf[j] : 0.f;
            if (j < 20 || tid < 64) s_in[l_off[j]] = v;
        }
        __syncthreads();                           // LDS ready
        if (chunk + 16 < 64) {                     // prefetch next chunk:
            const float* nb = inb + (chunk + 16) * S * S;
#pragma unroll
            for (int j = 0; j < NLD; ++j) pf[j] = nb[g_off[j]];
        }
#pragma unroll 4
        for (int ci = 0; ci < 16; ++ci) {
            const float* sp = &s_in[ci * 342 + ty * 19 + tx];
            float xw[9];
#pragma unroll
            for (int r = 0; r < 3; ++r)
#pragma unroll
                for (int c = 0; c < 3; ++c)
                    xw[r * 3 + c] = sp[r * 19 + c];
            const float* wp = &s_w[(chunk + ci) * 9 * OCB];
#pragma unroll
            for (int t = 0; t < 9; ++t) {
                float xv = xw[t];
                if constexpr (OCB == 4) {
                    float4 wv = *(const float4*)&wp[t * 4];
                    acc[0] += xv * wv.x;
                    acc[1] += xv * wv.y;
                    acc[2] += xv * wv.z;
                    acc[3] += xv * wv.w;
                } else {
                    float2 wv = *(const float2*)&wp[t * 2];
                    acc[0] += xv * wv.x;
                    acc[1] += xv * wv.y;
                }
            }
        }
    }

    const int h = th + ty, w = tw + tx;
#pragma unroll
    for (int k = 0; k < OCB; ++k) {
        int oc = oc0 + k;
        float v = acc[k] + bias[oc];
        if (lrelu) v = v > 0.f ? v : 0.1f * v;
        long off = ((long)(n * 64 + oc) * S + h) * S + w;
        if (res) v += res[off];
        out[off] = v;
    }
}

// 1x1 conv 64 -> 576 at 32x32. Block: 256 px, 8 oc. Weights in LDS.
__global__ __launch_bounds__(256) void conv1x1_k(
    const float* __restrict__ in, const float* __restrict__ w,
    const float* __restrict__ b, float* __restrict__ out) {
    __shared__ float s_in[32 * 256];               // 32 KB
    __shared__ __align__(16) float s_w[64 * 8];    // [ci][8oc] 2 KB
    const int tid = threadIdx.x;
    const int p0 = blockIdx.x * 256;               // 4 tiles of 1024 px
    const int cog = blockIdx.y;                    // 72 groups of 8
    const int n = blockIdx.z;

    for (int idx = tid; idx < 512; idx += 256) {   // coalesced: w[cog*8 .. +8][64]
        int j = idx >> 6;
        int ci = idx & 63;
        s_w[ci * 8 + j] = w[(long)cog * 512 + idx];
    }

    float acc[8];
#pragma unroll
    for (int i = 0; i < 8; ++i) acc[i] = b[cog * 8 + i];

    // prefetch chunk 0 into regs, pipeline across the 2 chunks
    float pf[32];
#pragma unroll
    for (int i = 0; i < 32; ++i)
        pf[i] = in[(long)(n * 64 + i) * 1024 + p0 + tid];

    for (int chunk = 0; chunk < 64; chunk += 32) {
        __syncthreads();
#pragma unroll
        for (int i = 0; i < 32; ++i) s_in[i * 256 + tid] = pf[i];
        __syncthreads();
        if (chunk + 32 < 64) {
#pragma unroll
            for (int i = 0; i < 32; ++i)
                pf[i] = in[(long)(n * 64 + chunk + 32 + i) * 1024 + p0 + tid];
        }
#pragma unroll 4
        for (int ci = 0; ci < 32; ++ci) {
            float v = s_in[ci * 256 + tid];
            float4 w0 = *(const float4*)&s_w[(chunk + ci) * 8];
            float4 w1 = *(const float4*)&s_w[(chunk + ci) * 8 + 4];
            acc[0] += v * w0.x; acc[1] += v * w0.y;
            acc[2] += v * w0.z; acc[3] += v * w0.w;
            acc[4] += v * w1.x; acc[5] += v * w1.y;
            acc[6] += v * w1.z; acc[7] += v * w1.w;
        }
    }
#pragma unroll
    for (int oc = 0; oc < 8; ++oc)
        out[(long)(n * 576 + cog * 8 + oc) * 1024 + p0 + tid] = acc[oc];
}

// Fused bilinear x8 upsample (half-pixel, edge clamp) + dynamic depthwise 3x3
// with replicate padding on x.
// Block: 256 thr = 8h x 32 w-strips (x4 px) for one cz. x tile in LDS
// (10 x 130 incl. halo, stride 132). 4-aligned w-strip shares floor(src_w)
// -> per tap the 4 outputs share all 4 bilinear corners.
__global__ __launch_bounds__(256) void dynconv_k(
    const float* __restrict__ x, const float* __restrict__ wt,
    float* __restrict__ out) {
    __shared__ __align__(16) float s_x[10 * 132]; // 5280 B
    const int tid = threadIdx.x;
    const int tx = tid & 31;                       // w-strip index (x4 px)
    const int ty = tid >> 5;                       // 0..7 row in tile
    const int tw = (blockIdx.x & 1) * 128;         // w tile origin
    const int th = (blockIdx.x >> 1) * 8;          // h tile origin
    const int cz = blockIdx.y;                     // n*64+c, 0..127

    const float* xb = x + (long)cz * 65536;
    // Stage x tile rows th-1..th+8, cols tw-1..tw+128, replicate-clamped.
    for (int idx = tid; idx < 1300; idx += 256) {  // 10 x 130
        int r = idx / 130;
        int c = idx - r * 130;
        int gh = min(max(th + r - 1, 0), 255);
        int gw = min(max(tw + c - 1, 0), 255);
        s_x[r * 132 + c] = xb[gh * 256 + gw];
    }

    const int h = th + ty;
    const int wbase = tw + tx * 4;

    // Bilinear source coords (half-pixel, matches jax.image.resize bilinear).
    float src_h = h * 0.125f - 0.4375f;
    int h0 = (int)floorf(src_h);
    float fh = src_h - (float)h0;
    int h0c = min(max(h0, 0), 31), h1c = min(max(h0 + 1, 0), 31);
    float src_w = wbase * 0.125f - 0.4375f;
    int w0 = (int)floorf(src_w);                   // shared by the 4 px
    float fw0 = src_w - (float)w0;
    int w0c = min(max(w0, 0), 31), w1c = min(max(w0 + 1, 0), 31);

    __syncthreads();

    // Load the 3x6 x-window once; all 9 taps index into it.
    float vals[3][6];
#pragma unroll
    for (int r = 0; r < 3; ++r) {
        const float* rp = &s_x[(ty + r) * 132 + tx * 4];
        float4 a = *(const float4*)rp;
        float2 b = *(const float2*)(rp + 4);
        vals[r][0] = a.x; vals[r][1] = a.y; vals[r][2] = a.z;
        vals[r][3] = a.w; vals[r][4] = b.x; vals[r][5] = b.y;
    }

    const float* wtb = wt + (long)cz * 9 * 1024;
    float acc[4] = {0.f, 0.f, 0.f, 0.f};
#pragma unroll
    for (int dh = 0; dh < 3; ++dh)
#pragma unroll
        for (int dw = 0; dw < 3; ++dw) {
            const float* p = wtb + (dh * 3 + dw) * 1024;
            float w00 = p[h0c * 32 + w0c], w01 = p[h0c * 32 + w1c];
            float w10 = p[h1c * 32 + w0c], w11 = p[h1c * 32 + w1c];
            float c0 = w00 + fh * (w10 - w00);     // h-lerp (shared fh)
            float c1 = w01 + fh * (w11 - w01);
            float d = c1 - c0;
#pragma unroll
            for (int j = 0; j < 4; ++j) {
                float wv = c0 + (fw0 + 0.125f * j) * d;
                acc[j] += vals[dh][j + dw] * wv;
            }
        }

    float4 o;
    o.x = acc[0]; o.y = acc[1]; o.z = acc[2]; o.w = acc[3];
    *(float4*)&out[(long)cz * 65536 + h * 256 + wbase] = o;
}

extern "C" void kernel_launch(void* const* d_in, const int* in_sizes, int n_in,
                              void* d_out, int out_size, void* d_ws, size_t ws_size,
                              hipStream_t stream) {
    const float* x    = (const float*)d_in[0];
    const float* b1w1 = (const float*)d_in[1];
    const float* b1b1 = (const float*)d_in[2];
    const float* b1w2 = (const float*)d_in[3];
    const float* b1b2 = (const float*)d_in[4];
    const float* b2w1 = (const float*)d_in[5];
    const float* b2b1 = (const float*)d_in[6];
    const float* b2w2 = (const float*)d_in[7];
    const float* b2b2 = (const float*)d_in[8];
    const float* tokw = (const float*)d_in[9];
    const float* tokb = (const float*)d_in[10];
    float* out = (float*)d_out;
    float* ws = (float*)d_ws;

    // Stage 1 buffers: [2,64,64,64] = 524288 floats each.
    float* A = ws;
    float* B = ws + 524288;
    float* T = ws + 1048576;
    // Stage 2 buffers overlay A (dead after maxpool reads B):
    float* P = ws;                  // [2,64,32,32] = 131072
    float* Q = ws + 131072;
    float* U = ws + 262144;
    float* WT = ws + 393216;        // [2,576,32,32] = 1179648 floats

    const int WSZ = 64 * 64 * 9;    // per-resblock weight stride

    avgpool4_k<<<2048, 256, 0, stream>>>(x, A);

    dim3 g64(4, 4, 32);             // z = n*16 + ocg (OCB=4)
    conv3x3_t<64, 4><<<g64, 256, 0, stream>>>(A, b1w1 + 0 * WSZ, b1b1 + 0,   nullptr, T, 1);
    conv3x3_t<64, 4><<<g64, 256, 0, stream>>>(T, b1w2 + 0 * WSZ, b1b2 + 0,   A,       B, 0);
    conv3x3_t<64, 4><<<g64, 256, 0, stream>>>(B, b1w1 + 1 * WSZ, b1b1 + 64,  nullptr, T, 1);
    conv3x3_t<64, 4><<<g64, 256, 0, stream>>>(T, b1w2 + 1 * WSZ, b1b2 + 64,  B,       A, 0);
    conv3x3_t<64, 4><<<g64, 256, 0, stream>>>(A, b1w1 + 2 * WSZ, b1b1 + 128, nullptr, T, 1);
    conv3x3_t<64, 4><<<g64, 256, 0, stream>>>(T, b1w2 + 2 * WSZ, b1b2 + 128, A,       B, 0);

    maxpool2_k<<<512, 256, 0, stream>>>(B, P);

    dim3 g32(2, 2, 64);             // z = n*32 + ocg (OCB=2)
    conv3x3_t<32, 2><<<g32, 256, 0, stream>>>(P, b2w1 + 0 * WSZ, b2b1 + 0,   nullptr, U, 1);
    conv3x3_t<32, 2><<<g32, 256, 0, stream>>>(U, b2w2 + 0 * WSZ, b2b2 + 0,   P,       Q, 0);
    conv3x3_t<32, 2><<<g32, 256, 0, stream>>>(Q, b2w1 + 1 * WSZ, b2b1 + 64,  nullptr, U, 1);
    conv3x3_t<32, 2><<<g32, 256, 0, stream>>>(U, b2w2 + 1 * WSZ, b2b2 + 64,  Q,       P, 0);
    conv3x3_t<32, 2><<<g32, 256, 0, stream>>>(P, b2w1 + 2 * WSZ, b2b1 + 128, nullptr, U, 1);
    conv3x3_t<32, 2><<<g32, 256, 0, stream>>>(U, b2w2 + 2 * WSZ, b2b2 + 128, P,       Q, 0);

    conv1x1_k<<<dim3(4, 72, 2), 256, 0, stream>>>(Q, tokw, tokb, WT);

    dynconv_k<<<dim3(64, 128), 256, 0, stream>>>(x, WT, out);
}